// Round 1
// baseline (1138.292 us; speedup 1.0000x reference)
//
#include <hip/hip_runtime.h>
#include <math.h>

#define S_N 3000
#define NCHUNK 16
#define CHUNK_COLS 1875   // 30000 / 16

__device__ __forceinline__ float sigm(float x) { return 1.0f / (1.0f + expf(-x)); }

#define BET(vv, ii, vx, ix) (((vv) > (vx)) || ((vv) == (vx) && (ii) < (ix)))

// streaming insert: candidates arrive in ascending index order, so strict > is
// exactly lax.top_k's lower-index-wins tie rule.
#define INS_STREAM(vv, ii) do { \
  float _v = (vv); int _i = (ii); \
  if (_v > v4) { \
    if (_v > v3) { v4 = v3; i4 = i3; \
      if (_v > v2) { v3 = v2; i3 = i2; \
        if (_v > v1) { v2 = v1; i2 = i1; \
          if (_v > v0) { v1 = v0; i1 = i0; v0 = _v; i0 = _i; } \
          else { v1 = _v; i1 = _i; } \
        } else { v2 = _v; i2 = _i; } \
      } else { v3 = _v; i3 = _i; } \
    } else { v4 = _v; i4 = _i; } \
  } \
} while (0)

// merge insert: arbitrary index order -> full (value desc, index asc) comparator
#define INS_FULL(vv, ii) do { \
  float _v = (vv); int _i = (ii); \
  if (BET(_v, _i, v4, i4)) { \
    if (BET(_v, _i, v3, i3)) { v4 = v3; i4 = i3; \
      if (BET(_v, _i, v2, i2)) { v3 = v2; i3 = i2; \
        if (BET(_v, _i, v1, i1)) { v2 = v1; i2 = i1; \
          if (BET(_v, _i, v0, i0)) { v1 = v0; i1 = i0; v0 = _v; i0 = _i; } \
          else { v1 = _v; i1 = _i; } \
        } else { v2 = _v; i2 = _i; } \
      } else { v3 = _v; i3 = _i; } \
    } else { v4 = _v; i4 = _i; } \
  } \
} while (0)

// ---------------------------------------------------------------------------
// Kernel 1: LSTM. 250 blocks x 1024 threads; each block owns 12 sequences.
// Waves 0-7: j = wave*64+lane, k-half 0; waves 8-15: same j, k-half 1.
// Each lane holds Whh[j][kh*64 .. kh*64+63] in 64 VGPRs (stationary).
// h broadcast from LDS (wave-uniform ds_read_b128). Partial gate sums go
// through LDS (P) to the activation phase, which owns c-state in registers.
// ---------------------------------------------------------------------------
__global__ __launch_bounds__(1024, 4) void lstm_kernel(
    const float* __restrict__ Xs, const float* __restrict__ Wih,
    const float* __restrict__ Whh, const float* __restrict__ bih,
    const float* __restrict__ bhh, float* __restrict__ H10)
{
  __shared__ float h_s[12 * 128];       // 6 KB
  __shared__ float P[2 * 12 * 512];     // 48 KB
  const int tid = threadIdx.x;
  const int s0 = blockIdx.x * 12;

  for (int i = tid; i < 12 * 128; i += 1024) h_s[i] = 0.0f;

  const int lane = tid & 63;
  const int wv = tid >> 6;
  const int j = (wv & 7) * 64 + lane;
  const int kh = wv >> 3;

  float4 w4[16];
  {
    const float4* wr = (const float4*)(Whh + j * 128 + kh * 64);
#pragma unroll
    for (int q = 0; q < 16; q++) w4[q] = wr[q];
  }
  float wi0 = 0, wi1 = 0, wi2 = 0, wi3 = 0, wi4 = 0, wi5 = 0, bj = 0;
  if (kh == 0) {
    wi0 = Wih[j * 6 + 0]; wi1 = Wih[j * 6 + 1]; wi2 = Wih[j * 6 + 2];
    wi3 = Wih[j * 6 + 3]; wi4 = Wih[j * 6 + 4]; wi5 = Wih[j * 6 + 5];
    bj = bih[j] + bhh[j];
  }

  float c0 = 0.0f, c1 = 0.0f;
  const int p0m = tid >> 7;      // 0..7
  const int pn = tid & 127;

  __syncthreads();

  for (int t = 0; t < 40; t++) {
    // ---- phase 1: gate pre-activations ----
#pragma unroll 1
    for (int m = 0; m < 12; m++) {
      float acc;
      if (kh == 0) {
        const float* xm = Xs + (size_t)(s0 + m) * 240 + t * 6;
        acc = bj;
        acc = fmaf(wi0, xm[0], acc); acc = fmaf(wi1, xm[1], acc);
        acc = fmaf(wi2, xm[2], acc); acc = fmaf(wi3, xm[3], acc);
        acc = fmaf(wi4, xm[4], acc); acc = fmaf(wi5, xm[5], acc);
      } else {
        acc = 0.0f;
      }
      const float4* hp = (const float4*)(h_s + m * 128 + kh * 64);
#pragma unroll
      for (int q = 0; q < 16; q++) {
        float4 h4 = hp[q];
        acc = fmaf(w4[q].x, h4.x, acc);
        acc = fmaf(w4[q].y, h4.y, acc);
        acc = fmaf(w4[q].z, h4.z, acc);
        acc = fmaf(w4[q].w, h4.w, acc);
      }
      P[(kh * 12 + m) * 512 + j] = acc;
    }
    __syncthreads();
    // ---- phase 2: activations, c/h update ----
    {
      const int m = p0m, n = pn;
      const float* Pa = P + m * 512;
      const float* Pb = P + (12 + m) * 512;
      float gi = Pa[n] + Pb[n];
      float gf = Pa[n + 128] + Pb[n + 128];
      float gg = Pa[n + 256] + Pb[n + 256];
      float go = Pa[n + 384] + Pb[n + 384];
      c0 = sigm(gf) * c0 + sigm(gi) * tanhf(gg);
      float h = sigm(go) * tanhf(c0);
      h_s[m * 128 + n] = h;
      if (t >= 30) H10[((size_t)(s0 + m) * 10 + (t - 30)) * 128 + n] = h;
    }
    if (tid < 512) {
      const int m = 8 + p0m, n = pn;   // p0m in 0..3 here
      const float* Pa = P + m * 512;
      const float* Pb = P + (12 + m) * 512;
      float gi = Pa[n] + Pb[n];
      float gf = Pa[n + 128] + Pb[n + 128];
      float gg = Pa[n + 256] + Pb[n + 256];
      float go = Pa[n + 384] + Pb[n + 384];
      c1 = sigm(gf) * c1 + sigm(gi) * tanhf(gg);
      float h = sigm(go) * tanhf(c1);
      h_s[m * 128 + n] = h;
      if (t >= 30) H10[((size_t)(s0 + m) * 10 + (t - 30)) * 128 + n] = h;
    }
    __syncthreads();
  }
}

// ---------------------------------------------------------------------------
// Kernel 2a: LayerNorm in-place over rows of H10 ([30000][128]).
// One wave per row.
// ---------------------------------------------------------------------------
__global__ __launch_bounds__(256) void ln_kernel(
    float* __restrict__ H, const float* __restrict__ g,
    const float* __restrict__ b, int nrows)
{
  int row = blockIdx.x * 4 + (threadIdx.x >> 6);
  int lane = threadIdx.x & 63;
  if (row >= nrows) return;
  float* hr = H + (size_t)row * 128;
  float x0 = hr[lane], x1 = hr[lane + 64];
  float s = x0 + x1;
  for (int off = 32; off > 0; off >>= 1) s += __shfl_xor(s, off);
  float mean = s * (1.0f / 128.0f);
  float d0 = x0 - mean, d1 = x1 - mean;
  float v = d0 * d0 + d1 * d1;
  for (int off = 32; off > 0; off >>= 1) v += __shfl_xor(v, off);
  float rstd = 1.0f / sqrtf(v * (1.0f / 128.0f) + 1e-5f);
  hr[lane] = d0 * rstd * g[lane] + b[lane];
  hr[lane + 64] = d1 * rstd * g[lane + 64] + b[lane + 64];
}

// ---------------------------------------------------------------------------
// Kernel 2b: Out[r] = l2norm(In_row[r] @ W^T). 16 rows per block, 256 threads.
// A-tile in LDS (broadcast reads); W rows streamed from L2 (one row per lane).
// ---------------------------------------------------------------------------
__global__ __launch_bounds__(256) void proj_kernel(
    const float* __restrict__ In, int inOff, int inStride, int nr,
    const float* __restrict__ W, float* __restrict__ Out)
{
  __shared__ float A_s[16 * 128];   // reused as output staging
  const int tid = threadIdx.x;
  const int r0 = blockIdx.x * 16;

  for (int i = tid; i < 16 * 32; i += 256) {
    int row = i >> 5, c = i & 31;
    int gr = r0 + row;
    float4 v = make_float4(0.f, 0.f, 0.f, 0.f);
    if (gr < nr)
      v = *(const float4*)(In + (size_t)inOff + (size_t)gr * inStride + c * 4);
    *(float4*)(A_s + row * 128 + c * 4) = v;
  }
  __syncthreads();

  const int j = tid & 127, rh = tid >> 7;
  const float* wrow = W + j * 128;
  float acc[8] = {0, 0, 0, 0, 0, 0, 0, 0};
  for (int kc = 0; kc < 32; kc++) {
    float4 wv4 = *(const float4*)(wrow + kc * 4);
#pragma unroll
    for (int i = 0; i < 8; i++) {
      float4 a4 = *(const float4*)(A_s + (rh * 8 + i) * 128 + kc * 4);
      acc[i] = fmaf(wv4.x, a4.x, acc[i]);
      acc[i] = fmaf(wv4.y, a4.y, acc[i]);
      acc[i] = fmaf(wv4.z, a4.z, acc[i]);
      acc[i] = fmaf(wv4.w, a4.w, acc[i]);
    }
  }
  __syncthreads();
#pragma unroll
  for (int i = 0; i < 8; i++) A_s[(rh * 8 + i) * 128 + j] = acc[i];
  __syncthreads();

  const int r = tid >> 4, qq = tid & 15;
  float ss = 0.0f;
#pragma unroll
  for (int i = 0; i < 8; i++) {
    float u = A_s[r * 128 + qq + i * 16];
    ss += u * u;
  }
  for (int off = 8; off > 0; off >>= 1) ss += __shfl_xor(ss, off);
  float scale = 1.0f / fmaxf(sqrtf(ss), 1e-12f);
  int gr = r0 + r;
  if (gr < nr) {
#pragma unroll
    for (int i = 0; i < 8; i++)
      Out[(size_t)gr * 128 + qq + i * 16] = A_s[r * 128 + qq + i * 16] * scale;
  }
}

// ---------------------------------------------------------------------------
// Kernel 3: attention scores + per-chunk top-5.
// grid (16 chunks, 47 target-blocks) x 256 threads.
// lanes <-> 64 targets (private top-5 in regs), waves <-> 8-col groups.
// ---------------------------------------------------------------------------
__global__ __launch_bounds__(256) void score_kernel(
    const float* __restrict__ Qn, const float* __restrict__ Kn,
    const int* __restrict__ tix, const float* __restrict__ log_temp,
    const float* __restrict__ lag_bias, float* __restrict__ part)
{
  __shared__ float Q_lds[64 * 132];   // padded stride 132: conflict-free
  __shared__ float B_lds[32 * 132];   // reused as merge buffer at the end
  const int tid = threadIdx.x;
  const int chunk = blockIdx.x;
  const int T0 = blockIdx.y * 64;
  const int lane = tid & 63, wv = tid >> 6;
  const int colBase0 = chunk * CHUNK_COLS;
  const int colEnd = colBase0 + CHUNK_COLS;

  // stage gathered Q rows (Qn[target_idx[T0+row]])
  for (int i = tid; i < 64 * 32; i += 256) {
    int row = i >> 5, c = i & 31;
    int tgt = T0 + row;
    float4 v = make_float4(0.f, 0.f, 0.f, 0.f);
    if (tgt < S_N) {
      int src = tix[tgt];
      v = *(const float4*)(Qn + (size_t)src * 128 + c * 4);
    }
    *(float4*)(Q_lds + row * 132 + c * 4) = v;
  }

  float invtemp;
  float lb[10];
  int myTix;
  {
    float temp = fminf(fmaxf(expf(log_temp[0]), 0.1f), 11.313708499f);
    invtemp = 1.0f / temp;
#pragma unroll
    for (int l = 0; l < 10; l++) lb[l] = lag_bias[l];
    myTix = (T0 + lane < S_N) ? tix[T0 + lane] : -1;
  }

  float v0 = -3e38f, v1 = -3e38f, v2 = -3e38f, v3 = -3e38f, v4 = -3e38f;
  int i0 = 0x7fffffff, i1 = 0x7fffffff, i2 = 0x7fffffff, i3 = 0x7fffffff,
      i4 = 0x7fffffff;

  const int nsub = (CHUNK_COLS + 31) / 32;   // 59
  for (int sp = 0; sp < nsub; sp++) {
    const int cb = colBase0 + sp * 32;
    __syncthreads();   // previous iteration's readers done (also covers Q stage)
    for (int i = tid; i < 32 * 32; i += 256) {
      int row = i >> 5, c = i & 31;
      int col = cb + row;
      float4 v = make_float4(0.f, 0.f, 0.f, 0.f);
      if (col < colEnd) v = *(const float4*)(Kn + (size_t)col * 128 + c * 4);
      *(float4*)(B_lds + row * 132 + c * 4) = v;
    }
    __syncthreads();

    float a[8] = {0, 0, 0, 0, 0, 0, 0, 0};
    const float* qrow = Q_lds + lane * 132;
    const float* brow = B_lds + (wv * 8) * 132;
    for (int kc = 0; kc < 32; kc++) {
      float4 q4 = *(const float4*)(qrow + kc * 4);
#pragma unroll
      for (int cc = 0; cc < 8; cc++) {
        float4 b4 = *(const float4*)(brow + cc * 132 + kc * 4);
        a[cc] = fmaf(q4.x, b4.x, a[cc]);
        a[cc] = fmaf(q4.y, b4.y, a[cc]);
        a[cc] = fmaf(q4.z, b4.z, a[cc]);
        a[cc] = fmaf(q4.w, b4.w, a[cc]);
      }
    }
#pragma unroll
    for (int cc = 0; cc < 8; cc++) {
      int col = cb + wv * 8 + cc;
      int scol = col / 10;
      int lcol = col - scol * 10;
      float vsc = a[cc] * invtemp + lb[lcol];
      if (col < colEnd && scol != myTix) {
        INS_STREAM(vsc, col);
      }
    }
  }

  __syncthreads();
  float* M = B_lds;   // [4][64][10]
  {
    float* my = M + (wv * 64 + lane) * 10;
    my[0] = v0; my[1] = __int_as_float(i0);
    my[2] = v1; my[3] = __int_as_float(i1);
    my[4] = v2; my[5] = __int_as_float(i2);
    my[6] = v3; my[7] = __int_as_float(i3);
    my[8] = v4; my[9] = __int_as_float(i4);
  }
  __syncthreads();
  if (wv == 0 && T0 + lane < S_N) {
    v0 = v1 = v2 = v3 = v4 = -3e38f;
    i0 = i1 = i2 = i3 = i4 = 0x7fffffff;
    for (int w = 0; w < 4; w++) {
      const float* src = M + (w * 64 + lane) * 10;
#pragma unroll
      for (int q = 0; q < 5; q++) {
        float vv = src[q * 2];
        int ii = __float_as_int(src[q * 2 + 1]);
        INS_FULL(vv, ii);
      }
    }
    float* dst = part + ((size_t)(T0 + lane) * NCHUNK + chunk) * 10;
    dst[0] = v0; dst[1] = __int_as_float(i0);
    dst[2] = v1; dst[3] = __int_as_float(i1);
    dst[4] = v2; dst[5] = __int_as_float(i2);
    dst[6] = v3; dst[7] = __int_as_float(i3);
    dst[8] = v4; dst[9] = __int_as_float(i4);
  }
}

// ---------------------------------------------------------------------------
// Kernel 4: merge 16 chunk top-5s -> global top-5, softmax, gather z, MLP.
// One thread per target.
// ---------------------------------------------------------------------------
__global__ __launch_bounds__(256) void final_kernel(
    const float* __restrict__ part, const float* __restrict__ Xraw,
    const float* __restrict__ W1, const float* __restrict__ b1,
    const float* __restrict__ W2, const float* __restrict__ b2,
    const float* __restrict__ W3, const float* __restrict__ b3,
    float* __restrict__ out)
{
  __shared__ float W1s[64 * 12];
  __shared__ float W2s[32 * 64];
  __shared__ float b1s[64];
  __shared__ float b2s[32];
  __shared__ float W3s[32];
  const int tid = threadIdx.x;
  for (int i = tid; i < 768; i += 256) W1s[i] = W1[i];
  for (int i = tid; i < 2048; i += 256) W2s[i] = W2[i];
  if (tid < 64) b1s[tid] = b1[tid];
  if (tid < 32) { b2s[tid] = b2[tid]; W3s[tid] = W3[tid]; }
  __syncthreads();

  int t = blockIdx.x * 256 + tid;
  if (t >= S_N) return;

  float v0 = -3e38f, v1 = -3e38f, v2 = -3e38f, v3 = -3e38f, v4 = -3e38f;
  int i0 = 0x7fffffff, i1 = 0x7fffffff, i2 = 0x7fffffff, i3 = 0x7fffffff,
      i4 = 0x7fffffff;
  const float* pp = part + (size_t)t * (NCHUNK * 10);
  for (int c = 0; c < NCHUNK * 5; c++) {
    float vv = pp[c * 2];
    int ii = __float_as_int(pp[c * 2 + 1]);
    INS_FULL(vv, ii);
  }

  // softmax over (v0..v4); v0 is the max by construction
  float e1 = expf(v1 - v0), e2 = expf(v2 - v0), e3 = expf(v3 - v0),
        e4 = expf(v4 - v0);
  float rs = 1.0f / (1.0f + e1 + e2 + e3 + e4);
  float w_[5] = {rs, e1 * rs, e2 * rs, e3 * rs, e4 * rs};
  int id[5] = {i0, i1, i2, i3, i4};

  float feat[12];
#pragma unroll
  for (int f = 0; f < 12; f++) feat[f] = 0.0f;
#pragma unroll
  for (int q = 0; q < 5; q++) {
    int iq = id[q];
    int s = iq / 10;
    int l = iq - 10 * s;
    int pos = 29 + l;   // clip(L-1-(L_MAX-l), 0, L-1)
    const float* zp = Xraw + (size_t)s * 240 + pos * 6;
#pragma unroll
    for (int f = 0; f < 6; f++) {
      float z = zp[f];
      feat[f] += w_[q] * z;
      if (q == 0) feat[6 + f] = z;
    }
  }

  float h1[64];
#pragma unroll 4
  for (int o = 0; o < 64; o++) {
    float acc = b1s[o];
    const float* wr = W1s + o * 12;
#pragma unroll
    for (int f = 0; f < 12; f++) acc = fmaf(wr[f], feat[f], acc);
    h1[o] = fmaxf(acc, 0.0f);
  }
  float r = b3[0];
#pragma unroll 2
  for (int o = 0; o < 32; o++) {
    float acc = b2s[o];
    const float* wr = W2s + o * 64;
#pragma unroll 8
    for (int k = 0; k < 64; k++) acc = fmaf(wr[k], h1[k], acc);
    r = fmaf(W3s[o], fmaxf(acc, 0.0f), r);
  }
  out[t] = r;
}

// ---------------------------------------------------------------------------
extern "C" void kernel_launch(void* const* d_in, const int* in_sizes, int n_in,
                              void* d_out, int out_size, void* d_ws,
                              size_t ws_size, hipStream_t stream) {
  const float* Xs   = (const float*)d_in[0];
  const float* Xraw = (const float*)d_in[1];
  const int*   tix  = (const int*)d_in[2];
  const float* Wih  = (const float*)d_in[3];
  const float* Whh  = (const float*)d_in[4];
  const float* bih  = (const float*)d_in[5];
  const float* bhh  = (const float*)d_in[6];
  const float* ln_g = (const float*)d_in[7];
  const float* ln_b = (const float*)d_in[8];
  const float* WQ   = (const float*)d_in[9];
  const float* WK   = (const float*)d_in[10];
  const float* log_temp = (const float*)d_in[11];
  const float* lag_bias = (const float*)d_in[12];
  const float* W1 = (const float*)d_in[13];
  const float* b1 = (const float*)d_in[14];
  const float* W2 = (const float*)d_in[15];
  const float* b2 = (const float*)d_in[16];
  const float* W3 = (const float*)d_in[17];
  const float* b3 = (const float*)d_in[18];
  float* outp = (float*)d_out;

  float* ws = (float*)d_ws;
  float* H10 = ws;                    // 3000*10*128 = 3,840,000
  float* Kn  = ws + 3840000;          // 30000*128   = 3,840,000
  float* Qn  = ws + 7680000;          // 3000*128    =   384,000
  float* part = ws + 8064000;         // 3000*16*10  =   480,000

  lstm_kernel<<<250, 1024, 0, stream>>>(Xs, Wih, Whh, bih, bhh, H10);
  ln_kernel<<<7500, 256, 0, stream>>>(H10, ln_g, ln_b, 30000);
  proj_kernel<<<1875, 256, 0, stream>>>(H10, 0, 128, 30000, WK, Kn);
  proj_kernel<<<188, 256, 0, stream>>>(H10, 9 * 128, 1280, 3000, WQ, Qn);
  {
    dim3 grid(NCHUNK, 47);
    score_kernel<<<grid, 256, 0, stream>>>(Qn, Kn, tix, log_temp, lag_bias,
                                           part);
  }
  final_kernel<<<12, 256, 0, stream>>>(part, Xraw, W1, b1, W2, b2, W3, b3,
                                       outp);
}